// Round 1
// baseline (554.595 us; speedup 1.0000x reference)
//
#include <hip/hip_runtime.h>
#include <math.h>

// ---------------- problem constants ----------------
// S=16, XN=YN=ZN=128, out z-len = 2*(128-1) = 254
// d_in order: Br(0), Bp(1), Bt(2), W1(3), b1(4), W2r(5), W2i(6), b2r(7), b2i(8)

// workspace layout (float offsets)
#define OFF_XR   0          // 3072
#define OFF_H    3072       // 1024
#define OFF_OR   4096       // 49152
#define OFF_OI   53248      // 49152
#define OFF_T    102400     // 3*128*16 complex = 12288 floats
#define OFF_G1   114688     // 3 fields * 2 arrays * 65536 complex = 786432 floats
#define OFF_G2   901120     // 9 arrays * 262144 complex = 4718592 floats
#define OFF_TAB  5619712    // 4 tables * 16*254 = 16256 floats
// total = 5,635,968 floats = ~21.5 MB

#define TWO_PI 6.28318530717958647692f

// ---------------- K0: z-axis irfft coefficient tables ----------------
// out(z) = sum_kz Gr[kz]*A[kz][z] + Gi[kz]*B[kz][z]
// plain: A = s*cos(th), B = -s*sin(th); dz: A = -s*kz*sin(th), B = -s*kz*cos(th)
// s = invN * (kz==0 ? 1 : 2), th = 2*pi*kz*z/254
__global__ void k_tabs(float* __restrict__ ws) {
    int gid = blockIdx.x * 256 + threadIdx.x;
    if (gid >= 16 * 254) return;
    int kz = gid / 254, z = gid - kz * 254;
    int m = (kz * z) % 254;
    float ang = TWO_PI * (float)m / 254.0f;
    float s, c;
    sincosf(ang, &s, &c);
    const float invN = 1.0f / (128.0f * 128.0f * 254.0f);
    float sc = invN * (kz == 0 ? 1.0f : 2.0f);
    float* tab = ws + OFF_TAB;
    tab[gid]           = sc * c;                 // A_plain
    tab[4064 + gid]    = -sc * s;                // B_plain
    tab[8128 + gid]    = -sc * (float)kz * s;    // A_dz
    tab[12192 + gid]   = -sc * (float)kz * c;    // B_dz
}

// ---------------- K1a: forward DFT along y (ky = 0..15) ----------------
// T[f][x][ky] = sum_y B_f[x,y] * e^{-2pi i ky y / 128};  f: 0->Bp, 1->-Bt, 2->Br
__global__ void k_dfty(const float* __restrict__ Br, const float* __restrict__ Bp,
                       const float* __restrict__ Bt, float* __restrict__ ws) {
    __shared__ float2 w[128];
    int t = threadIdx.x;
    if (t < 128) {
        float s, c;
        sincosf(-TWO_PI * (float)t / 128.0f, &s, &c);
        w[t] = make_float2(c, s);
    }
    __syncthreads();
    int gid = blockIdx.x * 256 + t;     // 0..6143
    int f = gid >> 11, x = (gid >> 4) & 127, ky = gid & 15;
    const float* B = (f == 0) ? Bp : ((f == 1) ? Bt : Br);
    float sgn = (f == 1) ? -1.0f : 1.0f;
    float ar = 0.f, ai = 0.f;
    for (int y = 0; y < 128; ++y) {
        float v = B[x * 128 + y];
        float2 ww = w[(ky * y) & 127];
        ar = fmaf(v, ww.x, ar);
        ai = fmaf(v, ww.y, ai);
    }
    float* T = ws + OFF_T;
    T[gid * 2]     = sgn * ar;
    T[gid * 2 + 1] = sgn * ai;
}

// ---------------- K1b: forward DFT along x (kx in {0..15, 112..127}) -> xr ----------------
__global__ void k_dftx(float* __restrict__ ws) {
    __shared__ float2 w[128];
    int t = threadIdx.x;
    if (t < 128) {
        float s, c;
        sincosf(-TWO_PI * (float)t / 128.0f, &s, &c);
        w[t] = make_float2(c, s);
    }
    __syncthreads();
    int gid = blockIdx.x * 256 + t;     // 0..1535
    int f = gid >> 9, kxi = (gid >> 4) & 31, ky = gid & 15;
    int kxe = (kxi < 16) ? kxi : kxi + 96;   // actual mode index mod 128
    const float* T = ws + OFF_T;
    float ar = 0.f, ai = 0.f;
    for (int x = 0; x < 128; ++x) {
        float tr = T[((f * 128 + x) * 16 + ky) * 2];
        float ti = T[((f * 128 + x) * 16 + ky) * 2 + 1];
        float2 ww = w[(kxe * x) & 127];
        ar = fmaf(tr, ww.x, fmaf(-ti, ww.y, ar));
        ai = fmaf(tr, ww.y, fmaf(ti, ww.x, ai));
    }
    int pos = f * 512 + ((kxi < 16) ? (kxi * 16 + ky) : (256 + (kxi - 16) * 16 + ky));
    ws[OFF_XR + pos]        = ar;
    ws[OFF_XR + 1536 + pos] = ai;
}

// ---------------- K2: h = sigmoid(W1 @ xr + b1) ----------------
__global__ void k_hidden(const float* __restrict__ W1, const float* __restrict__ b1,
                         float* __restrict__ ws) {
    int t = threadIdx.x, row = blockIdx.x;
    const float* xr = ws + OFF_XR;
    const float* Wr = W1 + (size_t)row * 3072;
    float acc = 0.f;
    #pragma unroll
    for (int j = 0; j < 12; ++j) {
        int col = t + 256 * j;
        acc = fmaf(Wr[col], xr[col], acc);
    }
    for (int off = 32; off; off >>= 1) acc += __shfl_down(acc, off);
    __shared__ float red[4];
    if ((t & 63) == 0) red[t >> 6] = acc;
    __syncthreads();
    if (t == 0) {
        float v = red[0] + red[1] + red[2] + red[3] + b1[row];
        ws[OFF_H + row] = 1.0f / (1.0f + expf(-v));
    }
}

// ---------------- K3: o = (W2r + i W2i) @ h + (b2r + i b2i) ----------------
// 4 rows per wave, 4 waves per block -> 16 rows/block, 3072 blocks.
// Rationale: with 1 row/wave each wave had only 12 independent float4 loads
// (192 B/lane) in flight before stalling -> Little's-law cap ~3 TB/s.
// 4 rows/wave quadruples outstanding bytes; h is loaded once per j and
// reused across rows. Per-lane, per-row summation order is unchanged.
__global__ void k_out(const float* __restrict__ W2r, const float* __restrict__ W2i,
                      const float* __restrict__ b2r, const float* __restrict__ b2i,
                      float* __restrict__ ws) {
    int t = threadIdx.x;
    int lane = t & 63, wid = t >> 6;
    int row0 = (blockIdx.x * 4 + wid) * 4;
    const float4* h4  = (const float4*)(ws + OFF_H);
    const float4* ar4 = (const float4*)W2r;
    const float4* ai4 = (const float4*)W2i;
    float accr[4] = {0.f, 0.f, 0.f, 0.f};
    float acci[4] = {0.f, 0.f, 0.f, 0.f};
    #pragma unroll
    for (int j = 0; j < 4; ++j) {
        int c = j * 64 + lane;
        float4 hv = h4[c];
        #pragma unroll
        for (int r = 0; r < 4; ++r) {
            float4 wr = ar4[(size_t)(row0 + r) * 256 + c];
            float4 wi = ai4[(size_t)(row0 + r) * 256 + c];
            accr[r] = fmaf(wr.x, hv.x, accr[r]);
            accr[r] = fmaf(wr.y, hv.y, accr[r]);
            accr[r] = fmaf(wr.z, hv.z, accr[r]);
            accr[r] = fmaf(wr.w, hv.w, accr[r]);
            acci[r] = fmaf(wi.x, hv.x, acci[r]);
            acci[r] = fmaf(wi.y, hv.y, acci[r]);
            acci[r] = fmaf(wi.z, hv.z, acci[r]);
            acci[r] = fmaf(wi.w, hv.w, acci[r]);
        }
    }
    #pragma unroll
    for (int off = 32; off; off >>= 1) {
        #pragma unroll
        for (int r = 0; r < 4; ++r) {
            accr[r] += __shfl_down(accr[r], off);
            acci[r] += __shfl_down(acci[r], off);
        }
    }
    if (lane == 0) {
        #pragma unroll
        for (int r = 0; r < 4; ++r) {
            ws[OFF_OR + row0 + r] = accr[r] + b2r[row0 + r];
            ws[OFF_OI + row0 + r] = acci[r] + b2i[row0 + r];
        }
    }
}

// ---------------- K4: stage 1 — inverse DFT along x over 32 corner modes ----------------
// G1a[f][x][kyi][kz] = sum_kxi F * e^{+2pi i kx x/128}
// G1b = sum_kxi (i*kxv) * F * e^{...}   (dx factor folded)
__global__ void k_stage1(float* __restrict__ ws) {
    __shared__ float2 w[128];
    int t = threadIdx.x;
    if (t < 128) {
        float s, c;
        sincosf(TWO_PI * (float)t / 128.0f, &s, &c);
        w[t] = make_float2(c, s);
    }
    __syncthreads();
    int f = blockIdx.y;
    int l = blockIdx.x * 256 + t;               // 0..65535
    int x = l >> 9, kyi = (l >> 4) & 31, kz = l & 15;
    int bhi = (kyi >> 4) & 1;
    int j = kyi & 15;
    const float* orr = ws + OFF_OR;
    const float* oii = ws + OFF_OI;
    float g1ar = 0.f, g1ai = 0.f, g1br = 0.f, g1bi = 0.f;
    for (int kxi = 0; kxi < 32; ++kxi) {
        int b = ((kxi >> 4) << 1) + bhi;
        int i = kxi & 15;
        int oidx = (((f * 4 + b) * 16 + i) * 16 + j) * 16 + kz;
        float Fr = orr[oidx], Fi = oii[oidx];
        int kxe = kxi + ((kxi >> 4) * 96);
        float kxv = (float)(kxi - ((kxi >> 4) << 5));
        float2 ww = w[(kxe * x) & 127];
        float a  = Fr * ww.x - Fi * ww.y;
        float bb = Fr * ww.y + Fi * ww.x;
        g1ar += a;  g1ai += bb;
        g1br = fmaf(-kxv, bb, g1br);
        g1bi = fmaf(kxv, a, g1bi);
    }
    float2* G1 = (float2*)(ws + OFF_G1);
    int base = f * 131072 + l;
    G1[base]         = make_float2(g1ar, g1ai);
    G1[base + 65536] = make_float2(g1br, g1bi);
}

// ---------------- K5: stage 2 — inverse DFT along y over 32 corner modes ----------------
// variants: 0 plain (-> field + dz), 1 dx (from G1b), 2 dy (i*kyv folded)
__global__ void k_stage2(float* __restrict__ ws) {
    __shared__ float2 w[128];
    int t = threadIdx.x;
    if (t < 128) {
        float s, c;
        sincosf(TWO_PI * (float)t / 128.0f, &s, &c);
        w[t] = make_float2(c, s);
    }
    __syncthreads();
    int f = blockIdx.y;
    int l = blockIdx.x * 256 + t;               // 0..262143
    int x = l >> 11, y = (l >> 4) & 127, kz = l & 15;
    const float2* G1 = (const float2*)(ws + OFF_G1) + f * 131072;
    float pr = 0.f, pi = 0.f, dxr = 0.f, dxi = 0.f, dyr = 0.f, dyi = 0.f;
    for (int kyi = 0; kyi < 32; ++kyi) {
        int gi = (x * 32 + kyi) * 16 + kz;
        float2 A  = G1[gi];
        float2 Bv = G1[65536 + gi];
        int kye = kyi + ((kyi >> 4) * 96);
        float kyv = (float)(kyi - ((kyi >> 4) << 5));
        float2 ww = w[(kye * y) & 127];
        float ar = A.x * ww.x - A.y * ww.y;
        float ai = A.x * ww.y + A.y * ww.x;
        pr += ar; pi += ai;
        dyr = fmaf(-kyv, ai, dyr);
        dyi = fmaf(kyv, ar, dyi);
        float br = Bv.x * ww.x - Bv.y * ww.y;
        float bi = Bv.x * ww.y + Bv.y * ww.x;
        dxr += br; dxi += bi;
    }
    float2* G2 = (float2*)(ws + OFF_G2);
    int fb = f * 3;
    G2[(size_t)(fb + 0) * 262144 + l] = make_float2(pr, pi);
    G2[(size_t)(fb + 1) * 262144 + l] = make_float2(dxr, dxi);
    G2[(size_t)(fb + 2) * 262144 + l] = make_float2(dyr, dyi);
}

// ---------------- K6: stage 3 — z-axis irfft (16 modes -> 254 points) + store ----------------
// grid (128 x, 9 arrays); block 256 (threads 0..253 own one z each)
__global__ __launch_bounds__(256) void k_stage3(const float* __restrict__ ws,
                                                float* __restrict__ out) {
    __shared__ float gs[4096];                  // [y][kz][re/im] for this (array, x)
    int t = threadIdx.x;
    int x = blockIdx.x, a = blockIdx.y;
    int f = a / 3, v = a - f * 3;
    const float* src = ws + OFF_G2 + ((size_t)a * 262144 + (size_t)x * 2048) * 2;
    const float4* s4 = (const float4*)src;
    float4* g4 = (float4*)gs;
    #pragma unroll
    for (int j = 0; j < 4; ++j) g4[t + 256 * j] = s4[t + 256 * j];
    __syncthreads();

    int z = t;
    bool active = (z < 254);
    float A1[16], B1[16], A2[16], B2[16];
    const float* tab = ws + OFF_TAB;
    if (active) {
        #pragma unroll
        for (int kz = 0; kz < 16; ++kz) {
            A1[kz] = tab[kz * 254 + z];
            B1[kz] = tab[4064 + kz * 254 + z];
            if (v == 0) {
                A2[kz] = tab[8128 + kz * 254 + z];
                B2[kz] = tab[12192 + kz * 254 + z];
            } else { A2[kz] = 0.f; B2[kz] = 0.f; }
        }
    } else {
        #pragma unroll
        for (int kz = 0; kz < 16; ++kz) { A1[kz] = B1[kz] = A2[kz] = B2[kz] = 0.f; }
    }

    int c1 = (v == 0) ? f : ((v == 1) ? 3 * f + 3 : 3 * f + 4);
    float* out1 = out + (size_t)(c1 * 128 + x) * 128 * 254;
    float* out2 = (v == 0) ? (out + (size_t)((3 * f + 5) * 128 + x) * 128 * 254) : nullptr;

    for (int y = 0; y < 128; ++y) {
        const float4* gp = (const float4*)(gs + y * 32);
        float acc1 = 0.f, acc2 = 0.f;
        #pragma unroll
        for (int q = 0; q < 8; ++q) {
            float4 gq = gp[q];
            acc1 = fmaf(gq.x, A1[2 * q], acc1);
            acc1 = fmaf(gq.y, B1[2 * q], acc1);
            acc1 = fmaf(gq.z, A1[2 * q + 1], acc1);
            acc1 = fmaf(gq.w, B1[2 * q + 1], acc1);
            if (v == 0) {
                acc2 = fmaf(gq.x, A2[2 * q], acc2);
                acc2 = fmaf(gq.y, B2[2 * q], acc2);
                acc2 = fmaf(gq.z, A2[2 * q + 1], acc2);
                acc2 = fmaf(gq.w, B2[2 * q + 1], acc2);
            }
        }
        if (active) {
            out1[(size_t)y * 254 + z] = acc1;
            if (v == 0) out2[(size_t)y * 254 + z] = acc2;
        }
    }
}

// ---------------- launch ----------------
extern "C" void kernel_launch(void* const* d_in, const int* in_sizes, int n_in,
                              void* d_out, int out_size, void* d_ws, size_t ws_size,
                              hipStream_t stream) {
    const float* Br  = (const float*)d_in[0];
    const float* Bp  = (const float*)d_in[1];
    const float* Bt  = (const float*)d_in[2];
    const float* W1  = (const float*)d_in[3];
    const float* b1  = (const float*)d_in[4];
    const float* W2r = (const float*)d_in[5];
    const float* W2i = (const float*)d_in[6];
    const float* b2r = (const float*)d_in[7];
    const float* b2i = (const float*)d_in[8];
    float* ws  = (float*)d_ws;
    float* out = (float*)d_out;

    k_tabs  <<<dim3(16),       dim3(256), 0, stream>>>(ws);
    k_dfty  <<<dim3(24),       dim3(256), 0, stream>>>(Br, Bp, Bt, ws);
    k_dftx  <<<dim3(6),        dim3(256), 0, stream>>>(ws);
    k_hidden<<<dim3(1024),     dim3(256), 0, stream>>>(W1, b1, ws);
    k_out   <<<dim3(3072),     dim3(256), 0, stream>>>(W2r, W2i, b2r, b2i, ws);
    k_stage1<<<dim3(256, 3),   dim3(256), 0, stream>>>(ws);
    k_stage2<<<dim3(1024, 3),  dim3(256), 0, stream>>>(ws);
    k_stage3<<<dim3(128, 9),   dim3(256), 0, stream>>>(ws, out);
}

// Round 3
// 515.752 us; speedup vs baseline: 1.0753x; 1.0753x over previous
//
#include <hip/hip_runtime.h>
#include <math.h>

// ---------------- problem constants ----------------
// S=16, XN=YN=ZN=128, out z-len = 2*(128-1) = 254
// d_in order: Br(0), Bp(1), Bt(2), W1(3), b1(4), W2r(5), W2i(6), b2r(7), b2i(8)

// workspace layout (float offsets)
#define OFF_XR   0          // 3072
#define OFF_H    3072       // 1024
#define OFF_OR   4096       // 49152
#define OFF_OI   53248      // 49152
#define OFF_T    102400     // 3*128*16 complex = 12288 floats
#define OFF_G1   114688     // 3 fields * 2 arrays * 65536 complex = 786432 floats
#define OFF_G2   901120     // 9 arrays * 262144 complex = 4718592 floats
#define OFF_TAB  5619712    // 4 tables * 16*254 = 16256 floats
// total = 5,635,968 floats = ~21.5 MB

#define TWO_PI 6.28318530717958647692f

// native vector type for nontemporal builtins (HIP float4 is a class -> rejected)
typedef float nfloat4 __attribute__((ext_vector_type(4)));

// ---------------- K0: z-axis irfft coefficient tables ----------------
__global__ void k_tabs(float* __restrict__ ws) {
    int gid = blockIdx.x * 256 + threadIdx.x;
    if (gid >= 16 * 254) return;
    int kz = gid / 254, z = gid - kz * 254;
    int m = (kz * z) % 254;
    float ang = TWO_PI * (float)m / 254.0f;
    float s, c;
    sincosf(ang, &s, &c);
    const float invN = 1.0f / (128.0f * 128.0f * 254.0f);
    float sc = invN * (kz == 0 ? 1.0f : 2.0f);
    float* tab = ws + OFF_TAB;
    tab[gid]           = sc * c;                 // A_plain
    tab[4064 + gid]    = -sc * s;                // B_plain
    tab[8128 + gid]    = -sc * (float)kz * s;    // A_dz
    tab[12192 + gid]   = -sc * (float)kz * c;    // B_dz
}

// ---------------- K1a: forward DFT along y (ky = 0..15) ----------------
__global__ void k_dfty(const float* __restrict__ Br, const float* __restrict__ Bp,
                       const float* __restrict__ Bt, float* __restrict__ ws) {
    __shared__ float2 w[128];
    int t = threadIdx.x;
    if (t < 128) {
        float s, c;
        sincosf(-TWO_PI * (float)t / 128.0f, &s, &c);
        w[t] = make_float2(c, s);
    }
    __syncthreads();
    int gid = blockIdx.x * 256 + t;     // 0..6143
    int f = gid >> 11, x = (gid >> 4) & 127, ky = gid & 15;
    const float* B = (f == 0) ? Bp : ((f == 1) ? Bt : Br);
    float sgn = (f == 1) ? -1.0f : 1.0f;
    float ar = 0.f, ai = 0.f;
    for (int y = 0; y < 128; ++y) {
        float v = B[x * 128 + y];
        float2 ww = w[(ky * y) & 127];
        ar = fmaf(v, ww.x, ar);
        ai = fmaf(v, ww.y, ai);
    }
    float* T = ws + OFF_T;
    T[gid * 2]     = sgn * ar;
    T[gid * 2 + 1] = sgn * ai;
}

// ---------------- K1b: forward DFT along x (kx in {0..15, 112..127}) -> xr ----------------
__global__ void k_dftx(float* __restrict__ ws) {
    __shared__ float2 w[128];
    int t = threadIdx.x;
    if (t < 128) {
        float s, c;
        sincosf(-TWO_PI * (float)t / 128.0f, &s, &c);
        w[t] = make_float2(c, s);
    }
    __syncthreads();
    int gid = blockIdx.x * 256 + t;     // 0..1535
    int f = gid >> 9, kxi = (gid >> 4) & 31, ky = gid & 15;
    int kxe = (kxi < 16) ? kxi : kxi + 96;   // actual mode index mod 128
    const float* T = ws + OFF_T;
    float ar = 0.f, ai = 0.f;
    for (int x = 0; x < 128; ++x) {
        float tr = T[((f * 128 + x) * 16 + ky) * 2];
        float ti = T[((f * 128 + x) * 16 + ky) * 2 + 1];
        float2 ww = w[(kxe * x) & 127];
        ar = fmaf(tr, ww.x, fmaf(-ti, ww.y, ar));
        ai = fmaf(tr, ww.y, fmaf(ti, ww.x, ai));
    }
    int pos = f * 512 + ((kxi < 16) ? (kxi * 16 + ky) : (256 + (kxi - 16) * 16 + ky));
    ws[OFF_XR + pos]        = ar;
    ws[OFF_XR + 1536 + pos] = ai;
}

// ---------------- K2: h = sigmoid(W1 @ xr + b1) ----------------
__global__ void k_hidden(const float* __restrict__ W1, const float* __restrict__ b1,
                         float* __restrict__ ws) {
    int t = threadIdx.x, row = blockIdx.x;
    const float* xr = ws + OFF_XR;
    const float* Wr = W1 + (size_t)row * 3072;
    float acc = 0.f;
    #pragma unroll
    for (int j = 0; j < 12; ++j) {
        int col = t + 256 * j;
        acc = fmaf(Wr[col], xr[col], acc);
    }
    for (int off = 32; off; off >>= 1) acc += __shfl_down(acc, off);
    __shared__ float red[4];
    if ((t & 63) == 0) red[t >> 6] = acc;
    __syncthreads();
    if (t == 0) {
        float v = red[0] + red[1] + red[2] + red[3] + b1[row];
        ws[OFF_H + row] = 1.0f / (1.0f + expf(-v));
    }
}

// ---------------- K3: o = (W2r + i W2i) @ h + (b2r + i b2i) ----------------
// One row per wave (round-0 structure — best measured), with NONTEMPORAL
// weight loads. Theory: the ~3.2 TB/s combined read rate is capped by the
// L2/L3 allocate-and-evict path (weights are read-once streaming data);
// the nt bit skips cache retention for the 402 MB weight stream. h stays
// a cached load (hot, shared by all waves). Arithmetic order unchanged.
__global__ void k_out(const float* __restrict__ W2r, const float* __restrict__ W2i,
                      const float* __restrict__ b2r, const float* __restrict__ b2i,
                      float* __restrict__ ws) {
    int t = threadIdx.x;
    int lane = t & 63, wid = t >> 6;
    int row = blockIdx.x * 4 + wid;
    const float4*  h4  = (const float4*)(ws + OFF_H);
    const nfloat4* ar4 = (const nfloat4*)W2r + (size_t)row * 256;
    const nfloat4* ai4 = (const nfloat4*)W2i + (size_t)row * 256;
    float accr = 0.f, acci = 0.f;
    #pragma unroll
    for (int j = 0; j < 4; ++j) {
        int c = j * 64 + lane;
        float4 hv = h4[c];
        nfloat4 wr = __builtin_nontemporal_load(&ar4[c]);
        nfloat4 wi = __builtin_nontemporal_load(&ai4[c]);
        accr = fmaf(wr.x, hv.x, accr); accr = fmaf(wr.y, hv.y, accr);
        accr = fmaf(wr.z, hv.z, accr); accr = fmaf(wr.w, hv.w, accr);
        acci = fmaf(wi.x, hv.x, acci); acci = fmaf(wi.y, hv.y, acci);
        acci = fmaf(wi.z, hv.z, acci); acci = fmaf(wi.w, hv.w, acci);
    }
    for (int off = 32; off; off >>= 1) {
        accr += __shfl_down(accr, off);
        acci += __shfl_down(acci, off);
    }
    if (lane == 0) {
        ws[OFF_OR + row] = accr + b2r[row];
        ws[OFF_OI + row] = acci + b2i[row];
    }
}

// ---------------- K4: stage 1 — inverse DFT along x over 32 corner modes ----------------
__global__ void k_stage1(float* __restrict__ ws) {
    __shared__ float2 w[128];
    int t = threadIdx.x;
    if (t < 128) {
        float s, c;
        sincosf(TWO_PI * (float)t / 128.0f, &s, &c);
        w[t] = make_float2(c, s);
    }
    __syncthreads();
    int f = blockIdx.y;
    int l = blockIdx.x * 256 + t;               // 0..65535
    int x = l >> 9, kyi = (l >> 4) & 31, kz = l & 15;
    int bhi = (kyi >> 4) & 1;
    int j = kyi & 15;
    const float* orr = ws + OFF_OR;
    const float* oii = ws + OFF_OI;
    float g1ar = 0.f, g1ai = 0.f, g1br = 0.f, g1bi = 0.f;
    for (int kxi = 0; kxi < 32; ++kxi) {
        int b = ((kxi >> 4) << 1) + bhi;
        int i = kxi & 15;
        int oidx = (((f * 4 + b) * 16 + i) * 16 + j) * 16 + kz;
        float Fr = orr[oidx], Fi = oii[oidx];
        int kxe = kxi + ((kxi >> 4) * 96);
        float kxv = (float)(kxi - ((kxi >> 4) << 5));
        float2 ww = w[(kxe * x) & 127];
        float a  = Fr * ww.x - Fi * ww.y;
        float bb = Fr * ww.y + Fi * ww.x;
        g1ar += a;  g1ai += bb;
        g1br = fmaf(-kxv, bb, g1br);
        g1bi = fmaf(kxv, a, g1bi);
    }
    float2* G1 = (float2*)(ws + OFF_G1);
    int base = f * 131072 + l;
    G1[base]         = make_float2(g1ar, g1ai);
    G1[base + 65536] = make_float2(g1br, g1bi);
}

// ---------------- K5: stage 2 — inverse DFT along y over 32 corner modes ----------------
__global__ void k_stage2(float* __restrict__ ws) {
    __shared__ float2 w[128];
    int t = threadIdx.x;
    if (t < 128) {
        float s, c;
        sincosf(TWO_PI * (float)t / 128.0f, &s, &c);
        w[t] = make_float2(c, s);
    }
    __syncthreads();
    int f = blockIdx.y;
    int l = blockIdx.x * 256 + t;               // 0..262143
    int x = l >> 11, y = (l >> 4) & 127, kz = l & 15;
    const float2* G1 = (const float2*)(ws + OFF_G1) + f * 131072;
    float pr = 0.f, pi = 0.f, dxr = 0.f, dxi = 0.f, dyr = 0.f, dyi = 0.f;
    for (int kyi = 0; kyi < 32; ++kyi) {
        int gi = (x * 32 + kyi) * 16 + kz;
        float2 A  = G1[gi];
        float2 Bv = G1[65536 + gi];
        int kye = kyi + ((kyi >> 4) * 96);
        float kyv = (float)(kyi - ((kyi >> 4) << 5));
        float2 ww = w[(kye * y) & 127];
        float ar = A.x * ww.x - A.y * ww.y;
        float ai = A.x * ww.y + A.y * ww.x;
        pr += ar; pi += ai;
        dyr = fmaf(-kyv, ai, dyr);
        dyi = fmaf(kyv, ar, dyi);
        float br = Bv.x * ww.x - Bv.y * ww.y;
        float bi = Bv.x * ww.y + Bv.y * ww.x;
        dxr += br; dxi += bi;
    }
    float2* G2 = (float2*)(ws + OFF_G2);
    int fb = f * 3;
    G2[(size_t)(fb + 0) * 262144 + l] = make_float2(pr, pi);
    G2[(size_t)(fb + 1) * 262144 + l] = make_float2(dxr, dxi);
    G2[(size_t)(fb + 2) * 262144 + l] = make_float2(dyr, dyi);
}

// ---------------- K6: stage 3 — z-axis irfft (16 modes -> 254 points) + store ----------------
__global__ __launch_bounds__(256) void k_stage3(const float* __restrict__ ws,
                                                float* __restrict__ out) {
    __shared__ float gs[4096];                  // [y][kz][re/im] for this (array, x)
    int t = threadIdx.x;
    int x = blockIdx.x, a = blockIdx.y;
    int f = a / 3, v = a - f * 3;
    const float* src = ws + OFF_G2 + ((size_t)a * 262144 + (size_t)x * 2048) * 2;
    const float4* s4 = (const float4*)src;
    float4* g4 = (float4*)gs;
    #pragma unroll
    for (int j = 0; j < 4; ++j) g4[t + 256 * j] = s4[t + 256 * j];
    __syncthreads();

    int z = t;
    bool active = (z < 254);
    float A1[16], B1[16], A2[16], B2[16];
    const float* tab = ws + OFF_TAB;
    if (active) {
        #pragma unroll
        for (int kz = 0; kz < 16; ++kz) {
            A1[kz] = tab[kz * 254 + z];
            B1[kz] = tab[4064 + kz * 254 + z];
            if (v == 0) {
                A2[kz] = tab[8128 + kz * 254 + z];
                B2[kz] = tab[12192 + kz * 254 + z];
            } else { A2[kz] = 0.f; B2[kz] = 0.f; }
        }
    } else {
        #pragma unroll
        for (int kz = 0; kz < 16; ++kz) { A1[kz] = B1[kz] = A2[kz] = B2[kz] = 0.f; }
    }

    int c1 = (v == 0) ? f : ((v == 1) ? 3 * f + 3 : 3 * f + 4);
    float* out1 = out + (size_t)(c1 * 128 + x) * 128 * 254;
    float* out2 = (v == 0) ? (out + (size_t)((3 * f + 5) * 128 + x) * 128 * 254) : nullptr;

    for (int y = 0; y < 128; ++y) {
        const float4* gp = (const float4*)(gs + y * 32);
        float acc1 = 0.f, acc2 = 0.f;
        #pragma unroll
        for (int q = 0; q < 8; ++q) {
            float4 gq = gp[q];
            acc1 = fmaf(gq.x, A1[2 * q], acc1);
            acc1 = fmaf(gq.y, B1[2 * q], acc1);
            acc1 = fmaf(gq.z, A1[2 * q + 1], acc1);
            acc1 = fmaf(gq.w, B1[2 * q + 1], acc1);
            if (v == 0) {
                acc2 = fmaf(gq.x, A2[2 * q], acc2);
                acc2 = fmaf(gq.y, B2[2 * q], acc2);
                acc2 = fmaf(gq.z, A2[2 * q + 1], acc2);
                acc2 = fmaf(gq.w, B2[2 * q + 1], acc2);
            }
        }
        if (active) {
            out1[(size_t)y * 254 + z] = acc1;
            if (v == 0) out2[(size_t)y * 254 + z] = acc2;
        }
    }
}

// ---------------- launch ----------------
extern "C" void kernel_launch(void* const* d_in, const int* in_sizes, int n_in,
                              void* d_out, int out_size, void* d_ws, size_t ws_size,
                              hipStream_t stream) {
    const float* Br  = (const float*)d_in[0];
    const float* Bp  = (const float*)d_in[1];
    const float* Bt  = (const float*)d_in[2];
    const float* W1  = (const float*)d_in[3];
    const float* b1  = (const float*)d_in[4];
    const float* W2r = (const float*)d_in[5];
    const float* W2i = (const float*)d_in[6];
    const float* b2r = (const float*)d_in[7];
    const float* b2i = (const float*)d_in[8];
    float* ws  = (float*)d_ws;
    float* out = (float*)d_out;

    k_tabs  <<<dim3(16),       dim3(256), 0, stream>>>(ws);
    k_dfty  <<<dim3(24),       dim3(256), 0, stream>>>(Br, Bp, Bt, ws);
    k_dftx  <<<dim3(6),        dim3(256), 0, stream>>>(ws);
    k_hidden<<<dim3(1024),     dim3(256), 0, stream>>>(W1, b1, ws);
    k_out   <<<dim3(12288),    dim3(256), 0, stream>>>(W2r, W2i, b2r, b2i, ws);
    k_stage1<<<dim3(256, 3),   dim3(256), 0, stream>>>(ws);
    k_stage2<<<dim3(1024, 3),  dim3(256), 0, stream>>>(ws);
    k_stage3<<<dim3(128, 9),   dim3(256), 0, stream>>>(ws, out);
}